// Round 9
// baseline (479.521 us; speedup 1.0000x reference)
//
#include <hip/hip_runtime.h>

// NTXentLoss, B=8192, D=128, T=0.1, idx=0. fp32 in, fp32 scalar out.
// R8 post-mortem: 64 KB one-shot staging regressed (2 blk/CU, no overlap,
// 1M global atomics). R9 = R6's best-measured structure (KP=32, 4-phase
// ping-pong, 34 KB LDS, 4 blk/CU) with: (i) identity slot layout (xor
// swizzle was the 2.1M-conflict delta vs R5/R8's measured-zero layouts),
// (ii) finalize fused into the tile kernel via stripe-completion counters
// (3 -> 2 dispatches), (iii) LDS rowsum + 128 global atomics/block kept.

#define BB 8192
#define DD 128
#define TM 128
#define TN 128
#define KP 32
#define NPH 4

typedef __attribute__((ext_vector_type(8))) short short8;
typedef __attribute__((ext_vector_type(4))) float floatx4;

#define GLOBAL_AS __attribute__((address_space(1)))
#define LDS_AS    __attribute__((address_space(3)))

static __device__ __forceinline__ float wave_sum(float v) {
#pragma unroll
    for (int off = 32; off > 0; off >>= 1) v += __shfl_xor(v, off, 64);
    return v;
}

static __device__ __forceinline__ unsigned short f2bf(float f) {
    unsigned int u = __float_as_uint(f);
    return (unsigned short)((u + 0x7FFFu + ((u >> 16) & 1u)) >> 16);
}

// ---- prep: normalize -> bf16 copies + 1/norm; zero denom/out/cnt --------
__global__ __launch_bounds__(256) void prep_kernel(
    const float* __restrict__ zis, const float* __restrict__ zjs,
    unsigned short* __restrict__ Zib, unsigned short* __restrict__ Zjb,
    float* __restrict__ rni, float* __restrict__ rnj,
    float* __restrict__ denom, int* __restrict__ cnt, float* __restrict__ out)
{
    int tid = threadIdx.x;
    if (blockIdx.x < 32) denom[blockIdx.x * 256 + tid] = 0.0f;   // 32*256 = BB
    if (blockIdx.x == 32 && tid < 64) cnt[tid] = 0;
    if (blockIdx.x == 0 && tid == 0) out[0] = 0.0f;

    int wave = tid >> 6, lane = tid & 63;
    int row = blockIdx.x * 4 + wave;
    const float* src; unsigned short* dst; float* rn; int r;
    if (row < BB) { src = zis; dst = Zib; rn = rni; r = row; }
    else          { src = zjs; dst = Zjb; rn = rnj; r = row - BB; }
    float2 u = *(const float2*)(src + (size_t)r * DD + lane * 2);
    float s = wave_sum(u.x * u.x + u.y * u.y);
    float sc = 1.0f / sqrtf(s);
    if (lane == 0) rn[r] = sc;
    ushort2 o; o.x = f2bf(u.x * sc); o.y = f2bf(u.y * sc);
    *(ushort2*)(dst + (size_t)r * DD + lane * 2) = o;
}

// ---- 128x128 MFMA tile, 4-phase ping-pong, identity LDS layout,
//      fused stripe finalize --------------------------------------------
__global__ __launch_bounds__(256) void mfma_tile_kernel(
    const unsigned short* __restrict__ Zjb,   // A: zj normalized
    const unsigned short* __restrict__ Zib,   // B: zi normalized
    const float* __restrict__ zis, const float* __restrict__ zjs,
    const float* __restrict__ rni, const float* __restrict__ rnj,
    const int* __restrict__ ilab, const int* __restrict__ jlab,
    const float* __restrict__ wts, const int* __restrict__ idxp,
    float* __restrict__ denom, int* __restrict__ cnt, float* __restrict__ out)
{
    __shared__ __align__(16) unsigned short At[2][TM * KP];  // 8 KB per buf
    __shared__ __align__(16) unsigned short Bt[2][TN * KP];
    __shared__ int   il[TN];
    __shared__ int   jl[TM];
    __shared__ float rowsum[TM];
    __shared__ int   lastflag;
    __shared__ float part[2];

    int tid  = threadIdx.x;
    int lane = tid & 63, wave = tid >> 6;
    int wm = wave >> 1, wn = wave & 1;        // 2x2 wave grid, 64x64 each
    int quad = lane >> 4, l15 = lane & 15;
    int i0 = blockIdx.y * TM, j0 = blockIdx.x * TN;

    if (tid < TN) { il[tid] = ilab[j0 + tid]; rowsum[tid] = 0.0f; }
    else          { jl[tid - 128] = jlab[i0 + tid - 128]; }

    floatx4 acc[4][4];
#pragma unroll
    for (int a = 0; a < 4; ++a)
#pragma unroll
        for (int b = 0; b < 4; ++b) acc[a][b] = (floatx4){0.f, 0.f, 0.f, 0.f};

    const unsigned short* srcA = Zjb + (size_t)i0 * DD;
    const unsigned short* srcB = Zib + (size_t)j0 * DD;

    // staging: 16 regions x 1 KB (16 rows x 32 k); lane l -> row l>>2,
    // kq l&3; HW writes lane l at base+16l => identity [row][kq] layout.
    int r_in = lane >> 2;
    int kq_l = lane & 3;

    auto stage = [&](int ph, int buf) {
#pragma unroll
        for (int t = 0; t < 4; ++t) {
            int g = wave + t * 4;                 // 0..15
            int isA = (g < 8) ? 1 : 0;
            int rbase = (g & 7) * 16;
            int grow = rbase + r_in;
            const unsigned short* gp = (isA ? srcA : srcB)
                + (size_t)grow * DD + ph * KP + kq_l * 8;
            unsigned short* lp = isA ? &At[buf][rbase * KP]
                                     : &Bt[buf][rbase * KP];
            __builtin_amdgcn_global_load_lds((const GLOBAL_AS void*)gp,
                                             (LDS_AS void*)lp, 16, 0, 0);
        }
    };

    auto compute = [&](int buf) {
        short8 af[4], bfr[4];
#pragma unroll
        for (int t = 0; t < 4; ++t) {
            int m = wm * 64 + t * 16 + l15;
            af[t] = *(const short8*)&At[buf][m * KP + quad * 8];
            int n = wn * 64 + t * 16 + l15;
            bfr[t] = *(const short8*)&Bt[buf][n * KP + quad * 8];
        }
#pragma unroll
        for (int mt = 0; mt < 4; ++mt)
#pragma unroll
            for (int nt = 0; nt < 4; ++nt)
                acc[mt][nt] = __builtin_amdgcn_mfma_f32_16x16x32_bf16(
                    af[mt], bfr[nt], acc[mt][nt], 0, 0, 0);
    };

    stage(0, 0);
    __syncthreads();
#pragma unroll
    for (int ph = 0; ph < NPH; ++ph) {
        if (ph + 1 < NPH) stage(ph + 1, (ph + 1) & 1);  // prefetch in flight
        compute(ph & 1);
        __syncthreads();
    }

    // epilogue: e = exp(10*c-10), mask, row-sum (C/D: col=l15, row=quad*4+r)
#pragma unroll
    for (int mt = 0; mt < 4; ++mt) {
#pragma unroll
        for (int r = 0; r < 4; ++r) {
            int rowl = wm * 64 + mt * 16 + quad * 4 + r;
            int jr = jl[rowl];
            float s = 0.0f;
#pragma unroll
            for (int nt = 0; nt < 4; ++nt) {
                int col = wn * 64 + nt * 16 + l15;
                float e = __expf(fmaf(acc[mt][nt][r], 10.0f, -10.0f));
                s += (il[col] != jr) ? e : 0.0f;
            }
            s += __shfl_xor(s, 1, 64);
            s += __shfl_xor(s, 2, 64);
            s += __shfl_xor(s, 4, 64);
            s += __shfl_xor(s, 8, 64);
            if (l15 == 0) atomicAdd(&rowsum[rowl], s);
        }
    }
    __syncthreads();
    if (tid < TM) atomicAdd(&denom[i0 + tid], rowsum[tid]);

    // ---- stripe completion: last col-block finalizes this row stripe ----
    __threadfence();                       // release our denom atomics
    if (tid == 0) {
        int old = atomicAdd(&cnt[blockIdx.y], 1);
        lastflag = (old == 63);
    }
    __syncthreads();
    if (lastflag) {
        __threadfence();                   // acquire side
        float l = 0.0f;
        if (tid < TM) {
            int i = i0 + tid;
            int j = idxp[0] + i;
            const float* za = zjs + (size_t)i * DD;
            const float* zb = zis + (size_t)j * DD;
            float s = 0.0f;
#pragma unroll 8
            for (int k = 0; k < DD; k += 4) {
                float4 a = *(const float4*)(za + k);
                float4 b = *(const float4*)(zb + k);
                s += a.x * b.x + a.y * b.y + a.z * b.z + a.w * b.w;
            }
            float p = s * rni[j] * rnj[i] * 10.0f;
            float dv = atomicAdd(&denom[i], 0.0f);   // coherent read
            float ls = 10.0f + logf(__expf(p - 10.0f) + dv) - p;
            float w = wts[j];
            l = (ls * w) / w;              // faithful to reference
        }
        float ws2 = wave_sum(l);
        if (lane == 0 && wave < 2) part[wave] = ws2;
        __syncthreads();
        if (tid == 0) atomicAdd(out, (part[0] + part[1]) * (1.0f / BB));
    }
}

// ---- launch --------------------------------------------------------------
extern "C" void kernel_launch(void* const* d_in, const int* in_sizes, int n_in,
                              void* d_out, int out_size, void* d_ws, size_t ws_size,
                              hipStream_t stream) {
    const float* zis = (const float*)d_in[0];
    const float* zjs = (const float*)d_in[1];
    const int* ilab = (const int*)d_in[2];
    const int* jlab = (const int*)d_in[3];
    const float* wts = (const float*)d_in[4];
    const int* idxp = (const int*)d_in[5];
    float* out = (float*)d_out;

    float* rni   = (float*)d_ws;
    float* rnj   = rni + BB;
    float* denom = rnj + BB;
    unsigned short* Zib = (unsigned short*)(denom + BB);  // [BB][DD] bf16
    unsigned short* Zjb = Zib + (size_t)BB * DD;
    int* cnt = (int*)(Zjb + (size_t)BB * DD);             // 64 ints

    prep_kernel<<<2 * BB / 4, 256, 0, stream>>>(
        zis, zjs, Zib, Zjb, rni, rnj, denom, cnt, out);
    mfma_tile_kernel<<<dim3(BB / TN, BB / TM), 256, 0, stream>>>(
        Zjb, Zib, zis, zjs, rni, rnj, ilab, jlab, wts, idxp, denom, cnt, out);
}

// Round 10
// 134.943 us; speedup vs baseline: 3.5535x; 3.5535x over previous
//
#include <hip/hip_runtime.h>

// NTXentLoss, B=8192, D=128, T=0.1, idx=0. fp32 in, fp32 scalar out.
// R9 post-mortem: per-block __threadfence (device-scope L2 wb/inv) serialized
// the whole grid -> 439 us. Reverted to 3 dispatches.
// R10 = R6 pipeline (KP=32, 4-phase ping-pong, 34 KB LDS) with COLUMN-MAJOR
// chunk layout [kq][row] in each 1 KB staging region: read quarter-waves get
// class = l15&7 in consecutive order (the R5/R8 measured-zero pattern),
// killing R6/R9's 2^21 conflict cycles without losing double-buffering.

#define BB 8192
#define DD 128
#define TM 128
#define TN 128
#define KP 32
#define NPH 4

typedef __attribute__((ext_vector_type(8))) short short8;
typedef __attribute__((ext_vector_type(4))) float floatx4;

#define GLOBAL_AS __attribute__((address_space(1)))
#define LDS_AS    __attribute__((address_space(3)))

static __device__ __forceinline__ float wave_sum(float v) {
#pragma unroll
    for (int off = 32; off > 0; off >>= 1) v += __shfl_xor(v, off, 64);
    return v;
}

static __device__ __forceinline__ unsigned short f2bf(float f) {
    unsigned int u = __float_as_uint(f);
    return (unsigned short)((u + 0x7FFFu + ((u >> 16) & 1u)) >> 16);
}

// ---- prep: normalize -> bf16 copies + 1/norm; zero denom and out ---------
__global__ __launch_bounds__(256) void prep_kernel(
    const float* __restrict__ zis, const float* __restrict__ zjs,
    unsigned short* __restrict__ Zib, unsigned short* __restrict__ Zjb,
    float* __restrict__ rni, float* __restrict__ rnj,
    float* __restrict__ denom, float* __restrict__ out)
{
    int tid = threadIdx.x;
    if (blockIdx.x < 32) denom[blockIdx.x * 256 + tid] = 0.0f;   // 32*256 = BB
    if (blockIdx.x == 0 && tid == 0) out[0] = 0.0f;

    int wave = tid >> 6, lane = tid & 63;
    int row = blockIdx.x * 4 + wave;
    const float* src; unsigned short* dst; float* rn; int r;
    if (row < BB) { src = zis; dst = Zib; rn = rni; r = row; }
    else          { src = zjs; dst = Zjb; rn = rnj; r = row - BB; }
    float2 u = *(const float2*)(src + (size_t)r * DD + lane * 2);
    float s = wave_sum(u.x * u.x + u.y * u.y);
    float sc = 1.0f / sqrtf(s);
    if (lane == 0) rn[r] = sc;
    ushort2 o; o.x = f2bf(u.x * sc); o.y = f2bf(u.y * sc);
    *(ushort2*)(dst + (size_t)r * DD + lane * 2) = o;
}

// ---- 128x128 MFMA tile, 4-phase ping-pong, column-major chunk layout -----
// Region = 1 KB = 16 rows x 4 kq-chunks (16 B each), stored [kq][row]:
// staging lane l fetches (row = l&15, kq = l>>4) -> lands at offset 16*l.
// Read (frag m, quad q): offset (q*16 + (m&15))*16 B in region m>>4 --
// quarter-wave spans 256 B contiguous, class order = l15&7 (R5 zero pattern).
__global__ __launch_bounds__(256) void mfma_tile_kernel(
    const unsigned short* __restrict__ Zjb,   // A: zj normalized
    const unsigned short* __restrict__ Zib,   // B: zi normalized
    const int* __restrict__ ilab, const int* __restrict__ jlab,
    float* __restrict__ denom)
{
    __shared__ __align__(16) unsigned short At[2][TM * KP];  // 8 KB per buf
    __shared__ __align__(16) unsigned short Bt[2][TN * KP];
    __shared__ int   il[TN];
    __shared__ int   jl[TM];
    __shared__ float rowsum[TM];

    int tid  = threadIdx.x;
    int lane = tid & 63, wave = tid >> 6;
    int wm = wave >> 1, wn = wave & 1;        // 2x2 wave grid, 64x64 each
    int quad = lane >> 4, l15 = lane & 15;
    int i0 = blockIdx.y * TM, j0 = blockIdx.x * TN;

    if (tid < TN) { il[tid] = ilab[j0 + tid]; rowsum[tid] = 0.0f; }
    else          { jl[tid - 128] = jlab[i0 + tid - 128]; }

    floatx4 acc[4][4];
#pragma unroll
    for (int a = 0; a < 4; ++a)
#pragma unroll
        for (int b = 0; b < 4; ++b) acc[a][b] = (floatx4){0.f, 0.f, 0.f, 0.f};

    const unsigned short* srcA = Zjb + (size_t)i0 * DD;
    const unsigned short* srcB = Zib + (size_t)j0 * DD;

    // staging lane map: row = l&15, kq = l>>4 (column-major in region)
    int r_in = lane & 15;
    int kq_l = lane >> 4;

    auto stage = [&](int ph, int buf) {
#pragma unroll
        for (int t = 0; t < 4; ++t) {
            int g = wave + t * 4;                 // 0..15
            int isA = (g < 8) ? 1 : 0;
            int rbase = (g & 7) * 16;
            const unsigned short* gp = (isA ? srcA : srcB)
                + (size_t)(rbase + r_in) * DD + ph * KP + kq_l * 8;
            unsigned short* lp = isA ? &At[buf][rbase * KP]
                                     : &Bt[buf][rbase * KP];
            __builtin_amdgcn_global_load_lds((const GLOBAL_AS void*)gp,
                                             (LDS_AS void*)lp, 16, 0, 0);
        }
    };

    auto compute = [&](int buf) {
        short8 af[4], bfr[4];
#pragma unroll
        for (int t = 0; t < 4; ++t) {
            int rgA = wm * 4 + t;                 // region of row m (m>>4)
            af[t]  = *(const short8*)&At[buf][rgA * 512 + (quad * 16 + l15) * 8];
            int rgB = wn * 4 + t;
            bfr[t] = *(const short8*)&Bt[buf][rgB * 512 + (quad * 16 + l15) * 8];
        }
#pragma unroll
        for (int mt = 0; mt < 4; ++mt)
#pragma unroll
            for (int nt = 0; nt < 4; ++nt)
                acc[mt][nt] = __builtin_amdgcn_mfma_f32_16x16x32_bf16(
                    af[mt], bfr[nt], acc[mt][nt], 0, 0, 0);
    };

    stage(0, 0);
    __syncthreads();
#pragma unroll
    for (int ph = 0; ph < NPH; ++ph) {
        if (ph + 1 < NPH) stage(ph + 1, (ph + 1) & 1);  // prefetch in flight
        compute(ph & 1);
        __syncthreads();
    }

    // epilogue: e = exp(10*c-10), mask, row-sum (C/D: col=l15, row=quad*4+r)
#pragma unroll
    for (int mt = 0; mt < 4; ++mt) {
#pragma unroll
        for (int r = 0; r < 4; ++r) {
            int rowl = wm * 64 + mt * 16 + quad * 4 + r;
            int jr = jl[rowl];
            float s = 0.0f;
#pragma unroll
            for (int nt = 0; nt < 4; ++nt) {
                int col = wn * 64 + nt * 16 + l15;
                float e = __expf(fmaf(acc[mt][nt][r], 10.0f, -10.0f));
                s += (il[col] != jr) ? e : 0.0f;
            }
            s += __shfl_xor(s, 1, 64);
            s += __shfl_xor(s, 2, 64);
            s += __shfl_xor(s, 4, 64);
            s += __shfl_xor(s, 8, 64);
            if (l15 == 0) atomicAdd(&rowsum[rowl], s);
        }
    }
    __syncthreads();
    if (tid < TM) atomicAdd(&denom[i0 + tid], rowsum[tid]);
}

// ---- fused pos + finalize (512 blocks, 1 atomic/block) -------------------
__global__ __launch_bounds__(256) void posfinal_kernel(
    const float* __restrict__ zis, const float* __restrict__ zjs,
    const float* __restrict__ rni, const float* __restrict__ rnj,
    const float* __restrict__ denom, const float* __restrict__ wts,
    const int* __restrict__ idxp, float* __restrict__ out)
{
    int wave = threadIdx.x >> 6, lane = threadIdx.x & 63;
    int idx = idxp[0];
    float ll = 0.0f;
#pragma unroll
    for (int t = 0; t < 4; ++t) {
        int i = blockIdx.x * 16 + wave * 4 + t;
        int j = idx + i;
        float2 a  = *(const float2*)(zjs + (size_t)i * DD + lane * 2);
        float2 b2 = *(const float2*)(zis + (size_t)j * DD + lane * 2);
        float s = wave_sum(a.x * b2.x + a.y * b2.y);
        if (lane == 0) {
            float p = s * rni[j] * rnj[i] * 10.0f;
            float l = 10.0f + logf(__expf(p - 10.0f) + denom[i]) - p;
            float w = wts[j];
            ll += (l * w) / w;    // faithful to reference's weighted mean
        }
    }
    __shared__ float part[4];
    if (lane == 0) part[wave] = ll;
    __syncthreads();
    if (threadIdx.x == 0)
        atomicAdd(out, (part[0] + part[1] + part[2] + part[3]) * (1.0f / BB));
}

// ---- launch --------------------------------------------------------------
extern "C" void kernel_launch(void* const* d_in, const int* in_sizes, int n_in,
                              void* d_out, int out_size, void* d_ws, size_t ws_size,
                              hipStream_t stream) {
    const float* zis = (const float*)d_in[0];
    const float* zjs = (const float*)d_in[1];
    const int* ilab = (const int*)d_in[2];
    const int* jlab = (const int*)d_in[3];
    const float* wts = (const float*)d_in[4];
    const int* idxp = (const int*)d_in[5];
    float* out = (float*)d_out;

    float* rni   = (float*)d_ws;
    float* rnj   = rni + BB;
    float* denom = rnj + BB;
    unsigned short* Zib = (unsigned short*)(denom + BB);  // [BB][DD] bf16
    unsigned short* Zjb = Zib + (size_t)BB * DD;

    prep_kernel<<<2 * BB / 4, 256, 0, stream>>>(
        zis, zjs, Zib, Zjb, rni, rnj, denom, out);
    mfma_tile_kernel<<<dim3(BB / TN, BB / TM), 256, 0, stream>>>(
        Zjb, Zib, ilab, jlab, denom);
    posfinal_kernel<<<BB / 16, 256, 0, stream>>>(
        zis, zjs, rni, rnj, denom, wts, idxp, out);
}